// Round 1
// baseline (586.166 us; speedup 1.0000x reference)
//
#include <hip/hip_runtime.h>

#define S_LEN 2048
#define HID 2048
#define NH 16
#define NKV 2
#define HD 256
#define MAXSEQ 4096
#define NALL 9216   // 8192 qg | 512 k | 512 v
#define RD 64

typedef __attribute__((ext_vector_type(8))) short short8_t;   // 8 bf16 (4 VGPRs)
typedef __attribute__((ext_vector_type(4))) float float4_t;   // MFMA C/D

__device__ __forceinline__ unsigned short f2b(float f) {
  union { float f; unsigned u; } v; v.f = f;
  unsigned u = v.u;
  return (unsigned short)((u + 0x7FFFu + ((u >> 16) & 1u)) >> 16);  // RNE, finite data
}

__device__ __forceinline__ void gload_lds16(const void* g, void* l) {
  __builtin_amdgcn_global_load_lds(
      (const __attribute__((address_space(1))) void*)g,
      (__attribute__((address_space(3))) void*)l, 16, 0, 0);
}

// ---------------- fp32 -> bf16 convert ----------------
__global__ void cvt_bf16(const float* __restrict__ src, unsigned short* __restrict__ dst, int n4) {
  int i = blockIdx.x * blockDim.x + threadIdx.x;
  if (i < n4) {
    float4 v = ((const float4*)src)[i];
    short4 o;
    o.x = (short)f2b(v.x); o.y = (short)f2b(v.y);
    o.z = (short)f2b(v.z); o.w = (short)f2b(v.w);
    ((short4*)dst)[i] = o;
  }
}

// ---------------- bf16 GEMM, C = A * B^T  (A: MxK, B: NxK row-major, C: MxN f32) ----------------
// m97 structure: 2-barrier K-loop, global_load_lds width=16, 16x16x32 bf16 MFMA.
template<int BM, int BN, int MI, int NI>
__global__ __launch_bounds__(256, 2) void gemm_bt(
    const unsigned short* __restrict__ A, const unsigned short* __restrict__ B,
    float* __restrict__ C, int M, int N, int K) {
  constexpr int BK = 32;
  __shared__ unsigned short As[BM * BK];
  __shared__ unsigned short Bs[BN * BK];
  const int tid = threadIdx.x;
  const int lane = tid & 63;
  const int w = tid >> 6;
  const int wr = w >> 1, wc = w & 1;
  const int l15 = lane & 15, l4 = lane >> 4;
  const int M0 = blockIdx.y * BM, N0 = blockIdx.x * BN;
  float4_t acc[MI][NI] = {};
  for (int kt = 0; kt < K; kt += BK) {
    __syncthreads();
#pragma unroll
    for (int i = 0; i < (BM*BK/8)/256; ++i) {
      int c = tid + i*256;                       // chunk: row = c>>2, 8-elem col group = c&3
      gload_lds16(A + (size_t)(M0 + (c>>2))*K + kt + (c&3)*8, (char*)As + c*16);
    }
#pragma unroll
    for (int i = 0; i < (BN*BK/8)/256; ++i) {
      int c = tid + i*256;
      gload_lds16(B + (size_t)(N0 + (c>>2))*K + kt + (c&3)*8, (char*)Bs + c*16);
    }
    __syncthreads();
    short8_t af[MI], bf[NI];
#pragma unroll
    for (int mi = 0; mi < MI; ++mi)
      af[mi] = *(const short8_t*)&As[(wr*(BM/2) + mi*16 + l15)*BK + l4*8];
#pragma unroll
    for (int ni = 0; ni < NI; ++ni)
      bf[ni] = *(const short8_t*)&Bs[(wc*(BN/2) + ni*16 + l15)*BK + l4*8];
#pragma unroll
    for (int mi = 0; mi < MI; ++mi)
#pragma unroll
      for (int ni = 0; ni < NI; ++ni)
        acc[mi][ni] = __builtin_amdgcn_mfma_f32_16x16x32_bf16(af[mi], bf[ni], acc[mi][ni], 0, 0, 0);
  }
  // C/D layout: col = lane&15, row = (lane>>4)*4 + r  [m89/m91 verified]
#pragma unroll
  for (int mi = 0; mi < MI; ++mi) {
    int rb = M0 + wr*(BM/2) + mi*16 + l4*4;
#pragma unroll
    for (int ni = 0; ni < NI; ++ni) {
      int col = N0 + wc*(BN/2) + ni*16 + l15;
#pragma unroll
      for (int r = 0; r < 4; ++r)
        C[(size_t)(rb + r)*N + col] = acc[mi][ni][r];
    }
  }
}

// ---------------- post: RMSNorm + RoPE + split + caches + V^T ----------------
// grid (S/4, 20): y = 0..15 q-head, 16..17 k, 18..19 v. one wave per (s,row).
__global__ void postproc(const float* __restrict__ C1,
                         const float* __restrict__ cosb, const float* __restrict__ sinb,
                         const float* __restrict__ qnw, const float* __restrict__ knw,
                         unsigned short* __restrict__ qb, unsigned short* __restrict__ kb,
                         unsigned short* __restrict__ vtb,
                         float* __restrict__ kcache, float* __restrict__ vcache) {
  const int w = threadIdx.x >> 6, lane = threadIdx.x & 63;
  const int s = blockIdx.x*4 + w;
  const int t = blockIdx.y;
  const int d = lane*4;
  const float* rowp;
  if (t < 16)      rowp = C1 + (size_t)s*NALL + t*512;           // q part of head t
  else if (t < 18) rowp = C1 + (size_t)s*NALL + 8192 + (t-16)*256;
  else             rowp = C1 + (size_t)s*NALL + 8704 + (t-18)*256;
  float4 x = *(const float4*)(rowp + d);
  if (t >= 18) {            // V: f32 cache + bf16 transposed (HD x S) for PV b-frags
    int kvi = t - 18;
    *(float4*)(vcache + (size_t)kvi*MAXSEQ*HD + (size_t)s*HD + d) = x;
    unsigned short* vt = vtb + (size_t)kvi*HD*S_LEN;
    vt[(size_t)(d+0)*S_LEN + s] = f2b(x.x);
    vt[(size_t)(d+1)*S_LEN + s] = f2b(x.y);
    vt[(size_t)(d+2)*S_LEN + s] = f2b(x.z);
    vt[(size_t)(d+3)*S_LEN + s] = f2b(x.w);
    return;
  }
  float ss = x.x*x.x + x.y*x.y + x.z*x.z + x.w*x.w;
#pragma unroll
  for (int o = 32; o >= 1; o >>= 1) ss += __shfl_xor(ss, o, 64);
  float rn = rsqrtf(ss*(1.0f/256.0f) + 1e-6f);
  const float* nw = (t < 16) ? qnw : knw;
  float4 g = *(const float4*)(nw + d);
  float4 y;
  y.x = x.x*rn*(1.f+g.x); y.y = x.y*rn*(1.f+g.y);
  y.z = x.z*rn*(1.f+g.z); y.w = x.w*rn*(1.f+g.w);
  // RoPE on dims < 64 (lanes 0..15); partner at d^32 lives at lane^8, same component
  float px = __shfl_xor(y.x, 8, 64);
  float py = __shfl_xor(y.y, 8, 64);
  float pz = __shfl_xor(y.z, 8, 64);
  float pw = __shfl_xor(y.w, 8, 64);
  if (lane < 16) {
    float sgn = (lane & 8) ? 1.f : -1.f;        // d>=32: +x[d-32]; d<32: -x[d+32]
    float4 cs = *(const float4*)(cosb + (size_t)s*RD + d);
    float4 sn = *(const float4*)(sinb + (size_t)s*RD + d);
    y.x = y.x*cs.x + sgn*px*sn.x;
    y.y = y.y*cs.y + sgn*py*sn.y;
    y.z = y.z*cs.z + sgn*pz*sn.z;
    y.w = y.w*cs.w + sgn*pw*sn.w;
  }
  if (t < 16) {
    const float qs = 0.0625f * 1.44269504088896f;   // SCALE * log2(e): softmax in exp2 domain
    short4 o;
    o.x = (short)f2b(y.x*qs); o.y = (short)f2b(y.y*qs);
    o.z = (short)f2b(y.z*qs); o.w = (short)f2b(y.w*qs);
    *(short4*)(qb + (size_t)t*S_LEN*HD + (size_t)s*HD + d) = o;
  } else {
    int kvi = t - 16;
    *(float4*)(kcache + (size_t)kvi*MAXSEQ*HD + (size_t)s*HD + d) = y;
    short4 o;
    o.x = (short)f2b(y.x); o.y = (short)f2b(y.y);
    o.z = (short)f2b(y.z); o.w = (short)f2b(y.w);
    *(short4*)(kb + (size_t)kvi*S_LEN*HD + (size_t)s*HD + d) = o;
  }
}

// ---------------- flash attention + fused sigmoid gate ----------------
// grid (32 q-tiles, 16 heads), 256 thr. Wave w owns q rows [q0+16w, q0+16w+16).
// LDS: Ks 64x256 bf16 (32KB) | VTs 256x64 bf16 (32KB); P (per-wave 16x64) aliases into Ks.
__global__ __launch_bounds__(256, 2) void attn_kernel(
    const unsigned short* __restrict__ qb, const unsigned short* __restrict__ kb,
    const unsigned short* __restrict__ vtb, const float* __restrict__ C1,
    unsigned short* __restrict__ attnb) {
  __shared__ char smem[65536];
  unsigned short* Ks  = (unsigned short*)smem;
  unsigned short* VTs = (unsigned short*)(smem + 32768);
  const int tid = threadIdx.x, lane = tid & 63, w = tid >> 6;
  const int l15 = lane & 15, l4 = lane >> 4;
  const int h = blockIdx.y, kv = h >> 3;     // GROUPS = 8
  const int qt = blockIdx.x;
  const int q0 = qt * 64;
  const unsigned short* Qb = qb + (size_t)h*S_LEN*HD;
  const unsigned short* Kb = kb + (size_t)kv*S_LEN*HD;
  const unsigned short* Vb = vtb + (size_t)kv*HD*S_LEN;
  const int qrow = q0 + w*16 + l15;
  short8_t qf[8];                             // Q fragment, A-layout: [m=l15][k=l4*8+j] per 32-k step
#pragma unroll
  for (int kk = 0; kk < 8; ++kk)
    qf[kk] = *(const short8_t*)(Qb + (size_t)qrow*HD + kk*32 + l4*8);
  float4_t oacc[16] = {};
  float m_run[4] = {-1e30f, -1e30f, -1e30f, -1e30f};
  float l_run[4] = {0.f, 0.f, 0.f, 0.f};
  for (int kbI = 0; kbI <= qt; ++kbI) {
    const int k0 = kbI * 64;
    __syncthreads();                          // prev iter's LDS reads done
#pragma unroll
    for (int i = 0; i < 8; ++i) {             // K tile: 64 rows x 256
      int c = tid + i*256;
      gload_lds16(Kb + (size_t)(k0 + (c>>5))*HD + (c&31)*8, (char*)Ks + c*16);
    }
#pragma unroll
    for (int i = 0; i < 8; ++i) {             // V^T tile: 256 rows x 64
      int c = tid + i*256;
      gload_lds16(Vb + (size_t)(c>>3)*S_LEN + k0 + (c&7)*8, (char*)VTs + c*16);
    }
    __syncthreads();                          // staging drained (compiler: waitcnt vmcnt(0) + barrier)
    float4_t sacc[4] = {};
#pragma unroll
    for (int nt = 0; nt < 4; ++nt)
#pragma unroll
      for (int kk = 0; kk < 8; ++kk) {
        short8_t bfr = *(const short8_t*)&Ks[(nt*16 + l15)*HD + kk*32 + l4*8];
        sacc[nt] = __builtin_amdgcn_mfma_f32_16x16x32_bf16(qf[kk], bfr, sacc[nt], 0, 0, 0);
      }
    if (kbI == qt) {                          // causal mask only on diagonal tile
#pragma unroll
      for (int nt = 0; nt < 4; ++nt)
#pragma unroll
        for (int r = 0; r < 4; ++r)
          if (nt*16 + l15 > w*16 + l4*4 + r) sacc[nt][r] = -1e30f;
    }
    float alpha[4], p[4][4];
#pragma unroll
    for (int r = 0; r < 4; ++r) {
      float m0 = fmaxf(fmaxf(sacc[0][r], sacc[1][r]), fmaxf(sacc[2][r], sacc[3][r]));
      m0 = fmaxf(m0, __shfl_xor(m0, 1, 64));
      m0 = fmaxf(m0, __shfl_xor(m0, 2, 64));
      m0 = fmaxf(m0, __shfl_xor(m0, 4, 64));
      m0 = fmaxf(m0, __shfl_xor(m0, 8, 64));  // row-max across the 16-lane col group
      float mnew = fmaxf(m_run[r], m0);
      alpha[r] = exp2f(m_run[r] - mnew);
      m_run[r] = mnew;
      float sum = 0.f;
#pragma unroll
      for (int nt = 0; nt < 4; ++nt) {
        p[nt][r] = exp2f(sacc[nt][r] - mnew);
        sum += p[nt][r];
      }
      sum += __shfl_xor(sum, 1, 64);
      sum += __shfl_xor(sum, 2, 64);
      sum += __shfl_xor(sum, 4, 64);
      sum += __shfl_xor(sum, 8, 64);
      l_run[r] = l_run[r]*alpha[r] + sum;
    }
#pragma unroll
    for (int nt2 = 0; nt2 < 16; ++nt2) {
      oacc[nt2][0] *= alpha[0];
      oacc[nt2][1] *= alpha[1];
      oacc[nt2][2] *= alpha[2];
      oacc[nt2][3] *= alpha[3];
    }
    __syncthreads();                          // all waves finished reading Ks; safe to alias P
    unsigned short* Pw = (unsigned short*)(smem + w*2048);   // 16x64 bf16, row-major
#pragma unroll
    for (int nt = 0; nt < 4; ++nt)
#pragma unroll
      for (int r = 0; r < 4; ++r)
        Pw[(l4*4 + r)*64 + nt*16 + l15] = f2b(p[nt][r]);     // D-layout -> A-layout via LDS
    __syncthreads();                          // P visible / lgkm drained
    short8_t pf0 = *(const short8_t*)&Pw[l15*64 + l4*8];
    short8_t pf1 = *(const short8_t*)&Pw[l15*64 + 32 + l4*8];
#pragma unroll
    for (int nt2 = 0; nt2 < 16; ++nt2) {
      short8_t v0 = *(const short8_t*)&VTs[(nt2*16 + l15)*64 + l4*8];
      short8_t v1 = *(const short8_t*)&VTs[(nt2*16 + l15)*64 + 32 + l4*8];
      oacc[nt2] = __builtin_amdgcn_mfma_f32_16x16x32_bf16(pf0, v0, oacc[nt2], 0, 0, 0);
      oacc[nt2] = __builtin_amdgcn_mfma_f32_16x16x32_bf16(pf1, v1, oacc[nt2], 0, 0, 0);
    }
  }
  float inv_l[4];
#pragma unroll
  for (int r = 0; r < 4; ++r) inv_l[r] = 1.f / l_run[r];
  const int srow0 = q0 + w*16 + l4*4;
#pragma unroll
  for (int nt2 = 0; nt2 < 16; ++nt2) {
    int dim = nt2*16 + l15;
#pragma unroll
    for (int r = 0; r < 4; ++r) {
      int srow = srow0 + r;
      float gv = C1[(size_t)srow*NALL + h*512 + 256 + dim];  // gate pre-activation
      float sg = 1.f / (1.f + __expf(-gv));
      attnb[(size_t)srow*(NH*HD) + h*HD + dim] = f2b(oacc[nt2][r] * inv_l[r] * sg);
    }
  }
}

extern "C" void kernel_launch(void* const* d_in, const int* in_sizes, int n_in,
                              void* d_out, int out_size, void* d_ws, size_t ws_size,
                              hipStream_t stream) {
  const float* hidden = (const float*)d_in[0];
  const float* cosb   = (const float*)d_in[1];
  const float* sinb   = (const float*)d_in[2];
  const float* qw     = (const float*)d_in[3];
  const float* kw     = (const float*)d_in[4];
  const float* vw     = (const float*)d_in[5];
  const float* ow     = (const float*)d_in[6];
  const float* qnw    = (const float*)d_in[7];
  const float* knw    = (const float*)d_in[8];
  float* out    = (float*)d_out;
  float* kcache = out + (size_t)S_LEN*HID;
  float* vcache = kcache + (size_t)NKV*MAXSEQ*HD;

  char* ws = (char*)d_ws;
  size_t off = 0;
  auto alloc = [&](size_t bytes) -> char* {
    char* p = ws + off; off += (bytes + 255) & ~(size_t)255; return p;
  };
  unsigned short* hidb  = (unsigned short*)alloc((size_t)S_LEN*HID*2);     //  8 MB
  unsigned short* wallb = (unsigned short*)alloc((size_t)NALL*HID*2);      // 36 MB (q|k|v weights)
  unsigned short* wob   = (unsigned short*)alloc((size_t)HID*NH*HD*2);     // 16 MB
  float*          C1    = (float*)alloc((size_t)S_LEN*NALL*4);             // 72 MB
  unsigned short* qb    = (unsigned short*)alloc((size_t)NH*S_LEN*HD*2);   // 16 MB
  unsigned short* kb    = (unsigned short*)alloc((size_t)NKV*S_LEN*HD*2);  //  2 MB
  unsigned short* vtb   = (unsigned short*)alloc((size_t)NKV*HD*S_LEN*2);  //  2 MB
  unsigned short* attnb = (unsigned short*)alloc((size_t)S_LEN*NH*HD*2);   // 16 MB

  // fp32 -> bf16 conversions (weights concatenated: rows 0..8191 q, 8192..8703 k, 8704..9215 v)
  cvt_bf16<<<(S_LEN*HID/4 + 255)/256, 256, 0, stream>>>(hidden, hidb, S_LEN*HID/4);
  cvt_bf16<<<(8192*HID/4 + 255)/256, 256, 0, stream>>>(qw, wallb, 8192*HID/4);
  cvt_bf16<<<(512*HID/4 + 255)/256, 256, 0, stream>>>(kw, wallb + (size_t)8192*HID, 512*HID/4);
  cvt_bf16<<<(512*HID/4 + 255)/256, 256, 0, stream>>>(vw, wallb + (size_t)8704*HID, 512*HID/4);
  cvt_bf16<<<(HID*NH*HD/4 + 255)/256, 256, 0, stream>>>(ow, wob, HID*NH*HD/4);

  // zero the cache pad rows [S, MAX_SEQ)
  for (int kvi = 0; kvi < NKV; ++kvi) {
    hipMemsetAsync(kcache + (size_t)kvi*MAXSEQ*HD + (size_t)S_LEN*HD, 0,
                   (size_t)(MAXSEQ - S_LEN)*HD*4, stream);
    hipMemsetAsync(vcache + (size_t)kvi*MAXSEQ*HD + (size_t)S_LEN*HD, 0,
                   (size_t)(MAXSEQ - S_LEN)*HD*4, stream);
  }

  // fused QKV projection: C1 = hidden @ [Wq|Wk|Wv]^T  (2048 x 9216)
  gemm_bt<128,128,4,4><<<dim3(NALL/128, S_LEN/128), 256, 0, stream>>>(
      hidb, wallb, C1, S_LEN, NALL, HID);

  // RMSNorm + RoPE + caches + V^T + q pre-scale
  postproc<<<dim3(S_LEN/4, 20), 256, 0, stream>>>(
      C1, cosb, sinb, qnw, knw, qb, kb, vtb, kcache, vcache);

  // flash attention + sigmoid gate -> attnb (S x H*HD bf16)
  attn_kernel<<<dim3(S_LEN/64, NH), 256, 0, stream>>>(qb, kb, vtb, C1, attnb);

  // hidden_out = attnb @ Wo^T  (2048 x 2048, K=4096)
  gemm_bt<64,128,2,4><<<dim3(HID/128, S_LEN/64), 256, 0, stream>>>(
      attnb, wob, out, S_LEN, HID, NH*HD);
}

// Round 2
// 517.530 us; speedup vs baseline: 1.1326x; 1.1326x over previous
//
#include <hip/hip_runtime.h>

#define S_LEN 2048
#define HID 2048
#define NH 16
#define NKV 2
#define HD 256
#define MAXSEQ 4096
#define NALL 9216   // 8192 qg | 512 k | 512 v
#define RD 64

typedef __attribute__((ext_vector_type(8))) short short8_t;   // 8 bf16 (4 VGPRs)
typedef __attribute__((ext_vector_type(4))) float float4_t;   // MFMA C/D

__device__ __forceinline__ unsigned short f2b(float f) {
  union { float f; unsigned u; } v; v.f = f;
  unsigned u = v.u;
  return (unsigned short)((u + 0x7FFFu + ((u >> 16) & 1u)) >> 16);  // RNE, finite data
}

__device__ __forceinline__ void gload_lds16(const void* g, void* l) {
  __builtin_amdgcn_global_load_lds(
      (const __attribute__((address_space(1))) void*)g,
      (__attribute__((address_space(3))) void*)l, 16, 0, 0);
}

// ---------------- fp32 -> bf16 convert ----------------
__global__ void cvt_bf16(const float* __restrict__ src, unsigned short* __restrict__ dst, int n4) {
  int i = blockIdx.x * blockDim.x + threadIdx.x;
  if (i < n4) {
    float4 v = ((const float4*)src)[i];
    short4 o;
    o.x = (short)f2b(v.x); o.y = (short)f2b(v.y);
    o.z = (short)f2b(v.z); o.w = (short)f2b(v.w);
    ((short4*)dst)[i] = o;
  }
}

// ---------------- bf16 GEMM, C = A * B^T  (A: MxK, B: NxK row-major, C: MxN f32) ----------------
// m97 structure: 2-barrier K-loop, global_load_lds width=16, 16x16x32 bf16 MFMA.
template<int BM, int BN, int MI, int NI>
__global__ __launch_bounds__(256, 2) void gemm_bt(
    const unsigned short* __restrict__ A, const unsigned short* __restrict__ B,
    float* __restrict__ C, int M, int N, int K) {
  constexpr int BK = 32;
  __shared__ unsigned short As[BM * BK];
  __shared__ unsigned short Bs[BN * BK];
  const int tid = threadIdx.x;
  const int lane = tid & 63;
  const int w = tid >> 6;
  const int wr = w >> 1, wc = w & 1;
  const int l15 = lane & 15, l4 = lane >> 4;
  const int M0 = blockIdx.y * BM, N0 = blockIdx.x * BN;
  float4_t acc[MI][NI] = {};
  for (int kt = 0; kt < K; kt += BK) {
    __syncthreads();
#pragma unroll
    for (int i = 0; i < (BM*BK/8)/256; ++i) {
      int c = tid + i*256;                       // chunk: row = c>>2, 8-elem col group = c&3
      gload_lds16(A + (size_t)(M0 + (c>>2))*K + kt + (c&3)*8, (char*)As + c*16);
    }
#pragma unroll
    for (int i = 0; i < (BN*BK/8)/256; ++i) {
      int c = tid + i*256;
      gload_lds16(B + (size_t)(N0 + (c>>2))*K + kt + (c&3)*8, (char*)Bs + c*16);
    }
    __syncthreads();
    short8_t af[MI], bf[NI];
#pragma unroll
    for (int mi = 0; mi < MI; ++mi)
      af[mi] = *(const short8_t*)&As[(wr*(BM/2) + mi*16 + l15)*BK + l4*8];
#pragma unroll
    for (int ni = 0; ni < NI; ++ni)
      bf[ni] = *(const short8_t*)&Bs[(wc*(BN/2) + ni*16 + l15)*BK + l4*8];
#pragma unroll
    for (int mi = 0; mi < MI; ++mi)
#pragma unroll
      for (int ni = 0; ni < NI; ++ni)
        acc[mi][ni] = __builtin_amdgcn_mfma_f32_16x16x32_bf16(af[mi], bf[ni], acc[mi][ni], 0, 0, 0);
  }
  // C/D layout: col = lane&15, row = (lane>>4)*4 + r  [m89/m91 verified]
#pragma unroll
  for (int mi = 0; mi < MI; ++mi) {
    int rb = M0 + wr*(BM/2) + mi*16 + l4*4;
#pragma unroll
    for (int ni = 0; ni < NI; ++ni) {
      int col = N0 + wc*(BN/2) + ni*16 + l15;
#pragma unroll
      for (int r = 0; r < 4; ++r)
        C[(size_t)(rb + r)*N + col] = acc[mi][ni][r];
    }
  }
}

// ---------------- post: RMSNorm + RoPE + split + caches + V^T ----------------
// grid (S/4, 20): y = 0..15 q-head, 16..17 k, 18..19 v. one wave per (s,row).
__global__ void postproc(const float* __restrict__ C1,
                         const float* __restrict__ cosb, const float* __restrict__ sinb,
                         const float* __restrict__ qnw, const float* __restrict__ knw,
                         unsigned short* __restrict__ qb, unsigned short* __restrict__ kb,
                         unsigned short* __restrict__ vtb,
                         float* __restrict__ kcache, float* __restrict__ vcache) {
  const int w = threadIdx.x >> 6, lane = threadIdx.x & 63;
  const int s = blockIdx.x*4 + w;
  const int t = blockIdx.y;
  const int d = lane*4;
  const float* rowp;
  if (t < 16)      rowp = C1 + (size_t)s*NALL + t*512;           // q part of head t
  else if (t < 18) rowp = C1 + (size_t)s*NALL + 8192 + (t-16)*256;
  else             rowp = C1 + (size_t)s*NALL + 8704 + (t-18)*256;
  float4 x = *(const float4*)(rowp + d);
  if (t >= 18) {            // V: f32 cache + bf16 transposed (HD x S) for PV b-frags
    int kvi = t - 18;
    *(float4*)(vcache + (size_t)kvi*MAXSEQ*HD + (size_t)s*HD + d) = x;
    unsigned short* vt = vtb + (size_t)kvi*HD*S_LEN;
    vt[(size_t)(d+0)*S_LEN + s] = f2b(x.x);
    vt[(size_t)(d+1)*S_LEN + s] = f2b(x.y);
    vt[(size_t)(d+2)*S_LEN + s] = f2b(x.z);
    vt[(size_t)(d+3)*S_LEN + s] = f2b(x.w);
    return;
  }
  float ss = x.x*x.x + x.y*x.y + x.z*x.z + x.w*x.w;
#pragma unroll
  for (int o = 32; o >= 1; o >>= 1) ss += __shfl_xor(ss, o, 64);
  float rn = rsqrtf(ss*(1.0f/256.0f) + 1e-6f);
  const float* nw = (t < 16) ? qnw : knw;
  float4 g = *(const float4*)(nw + d);
  float4 y;
  y.x = x.x*rn*(1.f+g.x); y.y = x.y*rn*(1.f+g.y);
  y.z = x.z*rn*(1.f+g.z); y.w = x.w*rn*(1.f+g.w);
  // RoPE on dims < 64 (lanes 0..15); partner at d^32 lives at lane^8, same component
  float px = __shfl_xor(y.x, 8, 64);
  float py = __shfl_xor(y.y, 8, 64);
  float pz = __shfl_xor(y.z, 8, 64);
  float pw = __shfl_xor(y.w, 8, 64);
  if (lane < 16) {
    float sgn = (lane & 8) ? 1.f : -1.f;        // d>=32: +x[d-32]; d<32: -x[d+32]
    float4 cs = *(const float4*)(cosb + (size_t)s*RD + d);
    float4 sn = *(const float4*)(sinb + (size_t)s*RD + d);
    y.x = y.x*cs.x + sgn*px*sn.x;
    y.y = y.y*cs.y + sgn*py*sn.y;
    y.z = y.z*cs.z + sgn*pz*sn.z;
    y.w = y.w*cs.w + sgn*pw*sn.w;
  }
  if (t < 16) {
    const float qs = 0.0625f * 1.44269504088896f;   // SCALE * log2(e): softmax in exp2 domain
    short4 o;
    o.x = (short)f2b(y.x*qs); o.y = (short)f2b(y.y*qs);
    o.z = (short)f2b(y.z*qs); o.w = (short)f2b(y.w*qs);
    *(short4*)(qb + (size_t)t*S_LEN*HD + (size_t)s*HD + d) = o;
  } else {
    int kvi = t - 16;
    *(float4*)(kcache + (size_t)kvi*MAXSEQ*HD + (size_t)s*HD + d) = y;
    short4 o;
    o.x = (short)f2b(y.x); o.y = (short)f2b(y.y);
    o.z = (short)f2b(y.z); o.w = (short)f2b(y.w);
    *(short4*)(kb + (size_t)kvi*S_LEN*HD + (size_t)s*HD + d) = o;
  }
}

// ---------------- flash attention + fused sigmoid gate ----------------
// 1-D grid 512 blocks, 256 thr. Wave w owns q rows [q0+16w, q0+16w+16).
// Balanced qt mapping: blocks b and b+256 have qt summing to 31 (anti-tail).
// LDS (XOR-swizzled, chunk' = chunk ^ (row&7), 16B chunks):
//   Ks 64x256 bf16 (32KB) | VTs 256x64 bf16 (32KB) | P 4 waves x 16x64 bf16 (8KB, private)
__global__ __launch_bounds__(256, 2) void attn_kernel(
    const unsigned short* __restrict__ qb, const unsigned short* __restrict__ kb,
    const unsigned short* __restrict__ vtb, const float* __restrict__ C1,
    unsigned short* __restrict__ attnb) {
  __shared__ char smem[73728];
  unsigned short* Ks  = (unsigned short*)smem;
  unsigned short* VTs = (unsigned short*)(smem + 32768);
  const int tid = threadIdx.x, lane = tid & 63, w = tid >> 6;
  const int l15 = lane & 15, l4 = lane >> 4;
  const int b = blockIdx.x;
  const int h = b & 15;
  const int u = b >> 4;
  const int qt = (u < 16) ? u : 47 - u;       // blocks b, b+256: qt sums to 31
  const int kv = h >> 3;                      // GROUPS = 8
  const int q0 = qt * 64;
  const unsigned short* Qb = qb + (size_t)h*S_LEN*HD;
  const unsigned short* Kb = kb + (size_t)kv*S_LEN*HD;
  const unsigned short* Vb = vtb + (size_t)kv*HD*S_LEN;
  unsigned short* Pw = (unsigned short*)(smem + 65536 + w*2048);   // private 16x64 bf16
  const int qrow = q0 + w*16 + l15;
  short8_t qf[8];                             // Q fragment, A-layout: [m=l15][k=l4*8+j] per 32-k step
#pragma unroll
  for (int kk = 0; kk < 8; ++kk)
    qf[kk] = *(const short8_t*)(Qb + (size_t)qrow*HD + kk*32 + l4*8);
  float4_t oacc[16] = {};
  float m_run[4] = {-1e30f, -1e30f, -1e30f, -1e30f};
  float l_run[4] = {0.f, 0.f, 0.f, 0.f};
  for (int kbI = 0; kbI <= qt; ++kbI) {
    const int k0 = kbI * 64;
    __syncthreads();                          // prev iter's LDS reads done
#pragma unroll
    for (int i = 0; i < 8; ++i) {             // K tile: 64 rows x 256, swizzled source col
      int c = tid + i*256;
      int row = c >> 5;
      gload_lds16(Kb + (size_t)(k0 + row)*HD + ((c & 31) ^ (row & 7))*8, (char*)Ks + c*16);
    }
#pragma unroll
    for (int i = 0; i < 8; ++i) {             // V^T tile: 256 rows x 64, swizzled source col
      int c = tid + i*256;
      int row = c >> 3;
      gload_lds16(Vb + (size_t)row*S_LEN + k0 + ((c & 7) ^ (row & 7))*8, (char*)VTs + c*16);
    }
    __syncthreads();                          // staging drained
    float4_t sacc[4] = {};
#pragma unroll
    for (int nt = 0; nt < 4; ++nt)
#pragma unroll
      for (int kk = 0; kk < 8; ++kk) {
        // row = nt*16+l15, global chunk kk*4+l4 -> swizzled ^ (l15&7): conflict-free
        short8_t bfr = *(const short8_t*)&Ks[(nt*16 + l15)*HD + (((kk*4 + l4) ^ (l15 & 7)))*8];
        sacc[nt] = __builtin_amdgcn_mfma_f32_16x16x32_bf16(qf[kk], bfr, sacc[nt], 0, 0, 0);
      }
    if (kbI == qt) {                          // causal mask only on diagonal tile
#pragma unroll
      for (int nt = 0; nt < 4; ++nt)
#pragma unroll
        for (int r = 0; r < 4; ++r)
          if (nt*16 + l15 > w*16 + l4*4 + r) sacc[nt][r] = -1e30f;
    }
    float alpha[4], p[4][4];
#pragma unroll
    for (int r = 0; r < 4; ++r) {
      float m0 = fmaxf(fmaxf(sacc[0][r], sacc[1][r]), fmaxf(sacc[2][r], sacc[3][r]));
      m0 = fmaxf(m0, __shfl_xor(m0, 1, 64));
      m0 = fmaxf(m0, __shfl_xor(m0, 2, 64));
      m0 = fmaxf(m0, __shfl_xor(m0, 4, 64));
      m0 = fmaxf(m0, __shfl_xor(m0, 8, 64));  // row-max across the 16-lane col group
      float mnew = fmaxf(m_run[r], m0);
      alpha[r] = exp2f(m_run[r] - mnew);
      m_run[r] = mnew;
      float sum = 0.f;
#pragma unroll
      for (int nt = 0; nt < 4; ++nt) {
        p[nt][r] = exp2f(sacc[nt][r] - mnew);
        sum += p[nt][r];
      }
      sum += __shfl_xor(sum, 1, 64);
      sum += __shfl_xor(sum, 2, 64);
      sum += __shfl_xor(sum, 4, 64);
      sum += __shfl_xor(sum, 8, 64);
      l_run[r] = l_run[r]*alpha[r] + sum;
    }
#pragma unroll
    for (int nt2 = 0; nt2 < 16; ++nt2) {
      oacc[nt2][0] *= alpha[0];
      oacc[nt2][1] *= alpha[1];
      oacc[nt2][2] *= alpha[2];
      oacc[nt2][3] *= alpha[3];
    }
    // P: D-layout -> A-layout via private LDS (no barrier needed, same-wave RAW)
#pragma unroll
    for (int nt = 0; nt < 4; ++nt)
#pragma unroll
      for (int r = 0; r < 4; ++r) {
        int prow = l4*4 + r;
        int pcol = nt*16 + l15;
        Pw[prow*64 + (((pcol >> 3) ^ (prow & 7)))*8 + (pcol & 7)] = f2b(p[nt][r]);
      }
    short8_t pf0 = *(const short8_t*)&Pw[l15*64 + ((l4 ^ (l15 & 7)))*8];
    short8_t pf1 = *(const short8_t*)&Pw[l15*64 + (((l4 ^ 4) ^ (l15 & 7)))*8];
#pragma unroll
    for (int nt2 = 0; nt2 < 16; ++nt2) {
      int vrow = nt2*16 + l15;
      short8_t v0 = *(const short8_t*)&VTs[vrow*64 + ((l4 ^ (l15 & 7)))*8];
      short8_t v1 = *(const short8_t*)&VTs[vrow*64 + (((l4 ^ 4) ^ (l15 & 7)))*8];
      oacc[nt2] = __builtin_amdgcn_mfma_f32_16x16x32_bf16(pf0, v0, oacc[nt2], 0, 0, 0);
      oacc[nt2] = __builtin_amdgcn_mfma_f32_16x16x32_bf16(pf1, v1, oacc[nt2], 0, 0, 0);
    }
  }
  float inv_l[4];
#pragma unroll
  for (int r = 0; r < 4; ++r) inv_l[r] = 1.f / l_run[r];
  const int srow0 = q0 + w*16 + l4*4;
#pragma unroll
  for (int nt2 = 0; nt2 < 16; ++nt2) {
    int dim = nt2*16 + l15;
#pragma unroll
    for (int r = 0; r < 4; ++r) {
      int srow = srow0 + r;
      float gv = C1[(size_t)srow*NALL + h*512 + 256 + dim];  // gate pre-activation
      float sg = 1.f / (1.f + __expf(-gv));
      attnb[(size_t)srow*(NH*HD) + h*HD + dim] = f2b(oacc[nt2][r] * inv_l[r] * sg);
    }
  }
}

extern "C" void kernel_launch(void* const* d_in, const int* in_sizes, int n_in,
                              void* d_out, int out_size, void* d_ws, size_t ws_size,
                              hipStream_t stream) {
  const float* hidden = (const float*)d_in[0];
  const float* cosb   = (const float*)d_in[1];
  const float* sinb   = (const float*)d_in[2];
  const float* qw     = (const float*)d_in[3];
  const float* kw     = (const float*)d_in[4];
  const float* vw     = (const float*)d_in[5];
  const float* ow     = (const float*)d_in[6];
  const float* qnw    = (const float*)d_in[7];
  const float* knw    = (const float*)d_in[8];
  float* out    = (float*)d_out;
  float* kcache = out + (size_t)S_LEN*HID;
  float* vcache = kcache + (size_t)NKV*MAXSEQ*HD;

  char* ws = (char*)d_ws;
  size_t off = 0;
  auto alloc = [&](size_t bytes) -> char* {
    char* p = ws + off; off += (bytes + 255) & ~(size_t)255; return p;
  };
  unsigned short* hidb  = (unsigned short*)alloc((size_t)S_LEN*HID*2);     //  8 MB
  unsigned short* wallb = (unsigned short*)alloc((size_t)NALL*HID*2);      // 36 MB (q|k|v weights)
  unsigned short* wob   = (unsigned short*)alloc((size_t)HID*NH*HD*2);     // 16 MB
  float*          C1    = (float*)alloc((size_t)S_LEN*NALL*4);             // 72 MB
  unsigned short* qb    = (unsigned short*)alloc((size_t)NH*S_LEN*HD*2);   // 16 MB
  unsigned short* kb    = (unsigned short*)alloc((size_t)NKV*S_LEN*HD*2);  //  2 MB
  unsigned short* vtb   = (unsigned short*)alloc((size_t)NKV*HD*S_LEN*2);  //  2 MB
  unsigned short* attnb = (unsigned short*)alloc((size_t)S_LEN*NH*HD*2);   // 16 MB

  // fp32 -> bf16 conversions (weights concatenated: rows 0..8191 q, 8192..8703 k, 8704..9215 v)
  cvt_bf16<<<(S_LEN*HID/4 + 255)/256, 256, 0, stream>>>(hidden, hidb, S_LEN*HID/4);
  cvt_bf16<<<(8192*HID/4 + 255)/256, 256, 0, stream>>>(qw, wallb, 8192*HID/4);
  cvt_bf16<<<(512*HID/4 + 255)/256, 256, 0, stream>>>(kw, wallb + (size_t)8192*HID, 512*HID/4);
  cvt_bf16<<<(512*HID/4 + 255)/256, 256, 0, stream>>>(vw, wallb + (size_t)8704*HID, 512*HID/4);
  cvt_bf16<<<(HID*NH*HD/4 + 255)/256, 256, 0, stream>>>(ow, wob, HID*NH*HD/4);

  // zero the cache pad rows [S, MAX_SEQ)
  for (int kvi = 0; kvi < NKV; ++kvi) {
    hipMemsetAsync(kcache + (size_t)kvi*MAXSEQ*HD + (size_t)S_LEN*HD, 0,
                   (size_t)(MAXSEQ - S_LEN)*HD*4, stream);
    hipMemsetAsync(vcache + (size_t)kvi*MAXSEQ*HD + (size_t)S_LEN*HD, 0,
                   (size_t)(MAXSEQ - S_LEN)*HD*4, stream);
  }

  // fused QKV projection: C1 = hidden @ [Wq|Wk|Wv]^T  (2048 x 9216)
  gemm_bt<128,128,4,4><<<dim3(NALL/128, S_LEN/128), 256, 0, stream>>>(
      hidb, wallb, C1, S_LEN, NALL, HID);

  // RMSNorm + RoPE + caches + V^T + q pre-scale
  postproc<<<dim3(S_LEN/4, 20), 256, 0, stream>>>(
      C1, cosb, sinb, qnw, knw, qb, kb, vtb, kcache, vcache);

  // flash attention + sigmoid gate -> attnb (S x H*HD bf16)
  attn_kernel<<<512, 256, 0, stream>>>(qb, kb, vtb, C1, attnb);

  // hidden_out = attnb @ Wo^T  (2048 x 2048, K=4096), 128x128 tile: 256 blocks
  gemm_bt<128,128,4,4><<<dim3(HID/128, S_LEN/128), 256, 0, stream>>>(
      attnb, wob, out, S_LEN, HID, NH*HD);
}

// Round 3
// 496.534 us; speedup vs baseline: 1.1805x; 1.0423x over previous
//
#include <hip/hip_runtime.h>

#define S_LEN 2048
#define HID 2048
#define NH 16
#define NKV 2
#define HD 256
#define MAXSEQ 4096
#define NALL 9216   // 8192 qg | 512 k | 512 v
#define RD 64

typedef __attribute__((ext_vector_type(8))) short short8_t;   // 8 bf16 (4 VGPRs)
typedef __attribute__((ext_vector_type(4))) float float4_t;   // MFMA C/D

// DPP cross-lane over a 16-lane row (VALU pipe, not LDS): xor1, xor2, half-mirror, mirror
#define DPPF(x, ctrl) __builtin_bit_cast(float, __builtin_amdgcn_update_dpp( \
    __builtin_bit_cast(int, x), __builtin_bit_cast(int, x), ctrl, 0xF, 0xF, false))

__device__ __forceinline__ unsigned short f2b(float f) {
  union { float f; unsigned u; } v; v.f = f;
  unsigned u = v.u;
  return (unsigned short)((u + 0x7FFFu + ((u >> 16) & 1u)) >> 16);  // RNE, finite data
}

__device__ __forceinline__ void gload_lds16(const void* g, void* l) {
  __builtin_amdgcn_global_load_lds(
      (const __attribute__((address_space(1))) void*)g,
      (__attribute__((address_space(3))) void*)l, 16, 0, 0);
}

// ---------------- fp32 -> bf16 convert ----------------
__global__ void cvt_bf16(const float* __restrict__ src, unsigned short* __restrict__ dst, int n4) {
  int i = blockIdx.x * blockDim.x + threadIdx.x;
  if (i < n4) {
    float4 v = ((const float4*)src)[i];
    short4 o;
    o.x = (short)f2b(v.x); o.y = (short)f2b(v.y);
    o.z = (short)f2b(v.z); o.w = (short)f2b(v.w);
    ((short4*)dst)[i] = o;
  }
}

// ---------------- bf16 GEMM, C = A * B^T  (A: MxK, B: NxK row-major, C: MxN f32) ----------------
// m97 structure: 2-barrier K-loop, global_load_lds width=16, 16x16x32 bf16 MFMA.
template<int BM, int BN, int MI, int NI>
__global__ __launch_bounds__(256, 2) void gemm_bt(
    const unsigned short* __restrict__ A, const unsigned short* __restrict__ B,
    float* __restrict__ C, int M, int N, int K) {
  constexpr int BK = 32;
  __shared__ unsigned short As[BM * BK];
  __shared__ unsigned short Bs[BN * BK];
  const int tid = threadIdx.x;
  const int lane = tid & 63;
  const int w = tid >> 6;
  const int wr = w >> 1, wc = w & 1;
  const int l15 = lane & 15, l4 = lane >> 4;
  const int M0 = blockIdx.y * BM, N0 = blockIdx.x * BN;
  float4_t acc[MI][NI] = {};
  for (int kt = 0; kt < K; kt += BK) {
    __syncthreads();
#pragma unroll
    for (int i = 0; i < (BM*BK/8)/256; ++i) {
      int c = tid + i*256;                       // chunk: row = c>>2, 8-elem col group = c&3
      gload_lds16(A + (size_t)(M0 + (c>>2))*K + kt + (c&3)*8, (char*)As + c*16);
    }
#pragma unroll
    for (int i = 0; i < (BN*BK/8)/256; ++i) {
      int c = tid + i*256;
      gload_lds16(B + (size_t)(N0 + (c>>2))*K + kt + (c&3)*8, (char*)Bs + c*16);
    }
    __syncthreads();
    short8_t af[MI], bf[NI];
#pragma unroll
    for (int mi = 0; mi < MI; ++mi)
      af[mi] = *(const short8_t*)&As[(wr*(BM/2) + mi*16 + l15)*BK + l4*8];
#pragma unroll
    for (int ni = 0; ni < NI; ++ni)
      bf[ni] = *(const short8_t*)&Bs[(wc*(BN/2) + ni*16 + l15)*BK + l4*8];
#pragma unroll
    for (int mi = 0; mi < MI; ++mi)
#pragma unroll
      for (int ni = 0; ni < NI; ++ni)
        acc[mi][ni] = __builtin_amdgcn_mfma_f32_16x16x32_bf16(af[mi], bf[ni], acc[mi][ni], 0, 0, 0);
  }
  // C/D layout: col = lane&15, row = (lane>>4)*4 + r  [m89/m91 verified]
#pragma unroll
  for (int mi = 0; mi < MI; ++mi) {
    int rb = M0 + wr*(BM/2) + mi*16 + l4*4;
#pragma unroll
    for (int ni = 0; ni < NI; ++ni) {
      int col = N0 + wc*(BN/2) + ni*16 + l15;
#pragma unroll
      for (int r = 0; r < 4; ++r)
        C[(size_t)(rb + r)*N + col] = acc[mi][ni][r];
    }
  }
}

// ---------------- post: RMSNorm + RoPE + split + caches + V^T ----------------
// grid (S/4, 20): y = 0..15 q-head, 16..17 k, 18..19 v. one wave per (s,row).
__global__ void postproc(const float* __restrict__ C1,
                         const float* __restrict__ cosb, const float* __restrict__ sinb,
                         const float* __restrict__ qnw, const float* __restrict__ knw,
                         unsigned short* __restrict__ qb, unsigned short* __restrict__ kb,
                         unsigned short* __restrict__ vtb,
                         float* __restrict__ kcache, float* __restrict__ vcache) {
  const int w = threadIdx.x >> 6, lane = threadIdx.x & 63;
  const int s = blockIdx.x*4 + w;
  const int t = blockIdx.y;
  const int d = lane*4;
  const float* rowp;
  if (t < 16)      rowp = C1 + (size_t)s*NALL + t*512;           // q part of head t
  else if (t < 18) rowp = C1 + (size_t)s*NALL + 8192 + (t-16)*256;
  else             rowp = C1 + (size_t)s*NALL + 8704 + (t-18)*256;
  float4 x = *(const float4*)(rowp + d);
  if (t >= 18) {            // V: f32 cache + bf16 transposed (HD x S) for PV b-frags
    int kvi = t - 18;
    *(float4*)(vcache + (size_t)kvi*MAXSEQ*HD + (size_t)s*HD + d) = x;
    unsigned short* vt = vtb + (size_t)kvi*HD*S_LEN;
    vt[(size_t)(d+0)*S_LEN + s] = f2b(x.x);
    vt[(size_t)(d+1)*S_LEN + s] = f2b(x.y);
    vt[(size_t)(d+2)*S_LEN + s] = f2b(x.z);
    vt[(size_t)(d+3)*S_LEN + s] = f2b(x.w);
    return;
  }
  float ss = x.x*x.x + x.y*x.y + x.z*x.z + x.w*x.w;
#pragma unroll
  for (int o = 32; o >= 1; o >>= 1) ss += __shfl_xor(ss, o, 64);
  float rn = rsqrtf(ss*(1.0f/256.0f) + 1e-6f);
  const float* nw = (t < 16) ? qnw : knw;
  float4 g = *(const float4*)(nw + d);
  float4 y;
  y.x = x.x*rn*(1.f+g.x); y.y = x.y*rn*(1.f+g.y);
  y.z = x.z*rn*(1.f+g.z); y.w = x.w*rn*(1.f+g.w);
  // RoPE on dims < 64 (lanes 0..15); partner at d^32 lives at lane^8, same component
  float px = __shfl_xor(y.x, 8, 64);
  float py = __shfl_xor(y.y, 8, 64);
  float pz = __shfl_xor(y.z, 8, 64);
  float pw = __shfl_xor(y.w, 8, 64);
  if (lane < 16) {
    float sgn = (lane & 8) ? 1.f : -1.f;        // d>=32: +x[d-32]; d<32: -x[d+32]
    float4 cs = *(const float4*)(cosb + (size_t)s*RD + d);
    float4 sn = *(const float4*)(sinb + (size_t)s*RD + d);
    y.x = y.x*cs.x + sgn*px*sn.x;
    y.y = y.y*cs.y + sgn*py*sn.y;
    y.z = y.z*cs.z + sgn*pz*sn.z;
    y.w = y.w*cs.w + sgn*pw*sn.w;
  }
  if (t < 16) {
    const float qs = 0.0625f * 1.44269504088896f;   // SCALE * log2(e): softmax in exp2 domain
    short4 o;
    o.x = (short)f2b(y.x*qs); o.y = (short)f2b(y.y*qs);
    o.z = (short)f2b(y.z*qs); o.w = (short)f2b(y.w*qs);
    *(short4*)(qb + (size_t)t*S_LEN*HD + (size_t)s*HD + d) = o;
  } else {
    int kvi = t - 16;
    *(float4*)(kcache + (size_t)kvi*MAXSEQ*HD + (size_t)s*HD + d) = y;
    short4 o;
    o.x = (short)f2b(y.x); o.y = (short)f2b(y.y);
    o.z = (short)f2b(y.z); o.w = (short)f2b(y.w);
    *(short4*)(kb + (size_t)kvi*S_LEN*HD + (size_t)s*HD + d) = o;
  }
}

// ---------------- flash attention + fused sigmoid gate ----------------
// 1-D grid 512 blocks, 256 thr. Wave w owns q rows [q0+16w, q0+16w+16).
// Balance map: qt(2i)+qt(2i+1)=31 (adjacent blocks pair heavy+light — placement-robust;
// under round-robin placement (b, b+256) pairs sum <= 38 vs 33 ideal).
// LDS (XOR-swizzled, chunk' = chunk ^ (row&7), 16B chunks):
//   Ks 64x256 bf16 (32KB) | VTs 256x64 bf16 (32KB) | P 4 waves x 16x64 bf16 (8KB, private)
__global__ __launch_bounds__(256, 2) void attn_kernel(
    const unsigned short* __restrict__ qb, const unsigned short* __restrict__ kb,
    const unsigned short* __restrict__ vtb, const float* __restrict__ C1,
    unsigned short* __restrict__ attnb) {
  __shared__ char smem[73728];
  unsigned short* Ks  = (unsigned short*)smem;
  unsigned short* VTs = (unsigned short*)(smem + 32768);
  const int tid = threadIdx.x, lane = tid & 63, w = tid >> 6;
  const int l15 = lane & 15, l4 = lane >> 4;
  const int b = blockIdx.x;
  const int i2 = b >> 1;
  const int h = i2 & 15;
  const int t16 = i2 >> 4;                    // 0..15
  const int qt = (b & 1) ? (31 - t16) : t16;  // adjacent blocks: qt sums to 31
  const int kv = h >> 3;                      // GROUPS = 8
  const int q0 = qt * 64;
  const unsigned short* Qb = qb + (size_t)h*S_LEN*HD;
  const unsigned short* Kb = kb + (size_t)kv*S_LEN*HD;
  const unsigned short* Vb = vtb + (size_t)kv*HD*S_LEN;
  unsigned short* Pw = (unsigned short*)(smem + 65536 + w*2048);   // private 16x64 bf16
  const int qrow = q0 + w*16 + l15;
  short8_t qf[8];                             // Q fragment, A-layout: [m=l15][k=l4*8+j] per 32-k step
#pragma unroll
  for (int kk = 0; kk < 8; ++kk)
    qf[kk] = *(const short8_t*)(Qb + (size_t)qrow*HD + kk*32 + l4*8);
  float4_t oacc[16] = {};
  float m_run[4] = {-1e30f, -1e30f, -1e30f, -1e30f};
  float l_run[4] = {0.f, 0.f, 0.f, 0.f};
  for (int kbI = 0; kbI <= qt; ++kbI) {
    const int k0 = kbI * 64;
    __syncthreads();                          // prev iter's LDS reads done
#pragma unroll
    for (int i = 0; i < 8; ++i) {             // K tile: 64 rows x 256, swizzled source col
      int c = tid + i*256;
      int row = c >> 5;
      gload_lds16(Kb + (size_t)(k0 + row)*HD + ((c & 31) ^ (row & 7))*8, (char*)Ks + c*16);
    }
#pragma unroll
    for (int i = 0; i < 8; ++i) {             // V^T tile: 256 rows x 64, swizzled source col
      int c = tid + i*256;
      int row = c >> 3;
      gload_lds16(Vb + (size_t)row*S_LEN + k0 + ((c & 7) ^ (row & 7))*8, (char*)VTs + c*16);
    }
    __syncthreads();                          // staging drained
    float4_t sacc[4] = {};
#pragma unroll
    for (int nt = 0; nt < 4; ++nt)
#pragma unroll
      for (int kk = 0; kk < 8; ++kk) {
        // row = nt*16+l15, global chunk kk*4+l4 -> swizzled ^ (l15&7): conflict-free
        short8_t bfr = *(const short8_t*)&Ks[(nt*16 + l15)*HD + (((kk*4 + l4) ^ (l15 & 7)))*8];
        sacc[nt] = __builtin_amdgcn_mfma_f32_16x16x32_bf16(qf[kk], bfr, sacc[nt], 0, 0, 0);
      }
    if (kbI == qt) {                          // causal mask only on diagonal tile
#pragma unroll
      for (int nt = 0; nt < 4; ++nt)
#pragma unroll
        for (int r = 0; r < 4; ++r)
          if (nt*16 + l15 > w*16 + l4*4 + r) sacc[nt][r] = -1e30f;
    }
    float alpha[4], p[4][4];
#pragma unroll
    for (int r = 0; r < 4; ++r) {
      float m0 = fmaxf(fmaxf(sacc[0][r], sacc[1][r]), fmaxf(sacc[2][r], sacc[3][r]));
      m0 = fmaxf(m0, DPPF(m0, 0xB1));         // quad_perm xor1
      m0 = fmaxf(m0, DPPF(m0, 0x4E));         // quad_perm xor2
      m0 = fmaxf(m0, DPPF(m0, 0x141));        // row_half_mirror
      m0 = fmaxf(m0, DPPF(m0, 0x140));        // row_mirror -> full 16-lane max
      float mnew = fmaxf(m_run[r], m0);
      alpha[r] = exp2f(m_run[r] - mnew);
      m_run[r] = mnew;
      float sum = 0.f;
#pragma unroll
      for (int nt = 0; nt < 4; ++nt) {
        p[nt][r] = exp2f(sacc[nt][r] - mnew);
        sum += p[nt][r];
      }
      sum += DPPF(sum, 0xB1);
      sum += DPPF(sum, 0x4E);
      sum += DPPF(sum, 0x141);
      sum += DPPF(sum, 0x140);                // full 16-lane sum
      l_run[r] = l_run[r]*alpha[r] + sum;
    }
#pragma unroll
    for (int nt2 = 0; nt2 < 16; ++nt2) {
      oacc[nt2][0] *= alpha[0];
      oacc[nt2][1] *= alpha[1];
      oacc[nt2][2] *= alpha[2];
      oacc[nt2][3] *= alpha[3];
    }
    // P: D-layout -> A-layout via private LDS (no barrier: same-wave RAW, lgkmcnt suffices)
#pragma unroll
    for (int nt = 0; nt < 4; ++nt)
#pragma unroll
      for (int r = 0; r < 4; ++r) {
        int prow = l4*4 + r;
        int pcol = nt*16 + l15;
        Pw[prow*64 + (((pcol >> 3) ^ (prow & 7)))*8 + (pcol & 7)] = f2b(p[nt][r]);
      }
    short8_t pf0 = *(const short8_t*)&Pw[l15*64 + ((l4 ^ (l15 & 7)))*8];
    short8_t pf1 = *(const short8_t*)&Pw[l15*64 + (((l4 ^ 4) ^ (l15 & 7)))*8];
#pragma unroll
    for (int nt2 = 0; nt2 < 16; ++nt2) {
      int vrow = nt2*16 + l15;
      short8_t v0 = *(const short8_t*)&VTs[vrow*64 + ((l4 ^ (l15 & 7)))*8];
      short8_t v1 = *(const short8_t*)&VTs[vrow*64 + (((l4 ^ 4) ^ (l15 & 7)))*8];
      oacc[nt2] = __builtin_amdgcn_mfma_f32_16x16x32_bf16(pf0, v0, oacc[nt2], 0, 0, 0);
      oacc[nt2] = __builtin_amdgcn_mfma_f32_16x16x32_bf16(pf1, v1, oacc[nt2], 0, 0, 0);
    }
  }
  float inv_l[4];
#pragma unroll
  for (int r = 0; r < 4; ++r) inv_l[r] = 1.f / l_run[r];
  const int srow0 = q0 + w*16 + l4*4;
#pragma unroll
  for (int nt2 = 0; nt2 < 16; ++nt2) {
    int dim = nt2*16 + l15;
#pragma unroll
    for (int r = 0; r < 4; ++r) {
      int srow = srow0 + r;
      float gv = C1[(size_t)srow*NALL + h*512 + 256 + dim];  // gate pre-activation
      float sg = 1.f / (1.f + __expf(-gv));
      attnb[(size_t)srow*(NH*HD) + h*HD + dim] = f2b(oacc[nt2][r] * inv_l[r] * sg);
    }
  }
}

extern "C" void kernel_launch(void* const* d_in, const int* in_sizes, int n_in,
                              void* d_out, int out_size, void* d_ws, size_t ws_size,
                              hipStream_t stream) {
  const float* hidden = (const float*)d_in[0];
  const float* cosb   = (const float*)d_in[1];
  const float* sinb   = (const float*)d_in[2];
  const float* qw     = (const float*)d_in[3];
  const float* kw     = (const float*)d_in[4];
  const float* vw     = (const float*)d_in[5];
  const float* ow     = (const float*)d_in[6];
  const float* qnw    = (const float*)d_in[7];
  const float* knw    = (const float*)d_in[8];
  float* out    = (float*)d_out;
  float* kcache = out + (size_t)S_LEN*HID;
  float* vcache = kcache + (size_t)NKV*MAXSEQ*HD;

  char* ws = (char*)d_ws;
  size_t off = 0;
  auto alloc = [&](size_t bytes) -> char* {
    char* p = ws + off; off += (bytes + 255) & ~(size_t)255; return p;
  };
  unsigned short* hidb  = (unsigned short*)alloc((size_t)S_LEN*HID*2);     //  8 MB
  unsigned short* wallb = (unsigned short*)alloc((size_t)NALL*HID*2);      // 36 MB (q|k|v weights)
  unsigned short* wob   = (unsigned short*)alloc((size_t)HID*NH*HD*2);     // 16 MB
  float*          C1    = (float*)alloc((size_t)S_LEN*NALL*4);             // 72 MB
  unsigned short* qb    = (unsigned short*)alloc((size_t)NH*S_LEN*HD*2);   // 16 MB
  unsigned short* kb    = (unsigned short*)alloc((size_t)NKV*S_LEN*HD*2);  //  2 MB
  unsigned short* vtb   = (unsigned short*)alloc((size_t)NKV*HD*S_LEN*2);  //  2 MB
  unsigned short* attnb = (unsigned short*)alloc((size_t)S_LEN*NH*HD*2);   // 16 MB

  // fp32 -> bf16 conversions (weights concatenated: rows 0..8191 q, 8192..8703 k, 8704..9215 v)
  cvt_bf16<<<(S_LEN*HID/4 + 255)/256, 256, 0, stream>>>(hidden, hidb, S_LEN*HID/4);
  cvt_bf16<<<(8192*HID/4 + 255)/256, 256, 0, stream>>>(qw, wallb, 8192*HID/4);
  cvt_bf16<<<(512*HID/4 + 255)/256, 256, 0, stream>>>(kw, wallb + (size_t)8192*HID, 512*HID/4);
  cvt_bf16<<<(512*HID/4 + 255)/256, 256, 0, stream>>>(vw, wallb + (size_t)8704*HID, 512*HID/4);
  cvt_bf16<<<(HID*NH*HD/4 + 255)/256, 256, 0, stream>>>(ow, wob, HID*NH*HD/4);

  // zero the cache pad rows [S, MAX_SEQ)
  for (int kvi = 0; kvi < NKV; ++kvi) {
    hipMemsetAsync(kcache + (size_t)kvi*MAXSEQ*HD + (size_t)S_LEN*HD, 0,
                   (size_t)(MAXSEQ - S_LEN)*HD*4, stream);
    hipMemsetAsync(vcache + (size_t)kvi*MAXSEQ*HD + (size_t)S_LEN*HD, 0,
                   (size_t)(MAXSEQ - S_LEN)*HD*4, stream);
  }

  // fused QKV projection: C1 = hidden @ [Wq|Wk|Wv]^T  (2048 x 9216)
  gemm_bt<128,128,4,4><<<dim3(NALL/128, S_LEN/128), 256, 0, stream>>>(
      hidb, wallb, C1, S_LEN, NALL, HID);

  // RMSNorm + RoPE + caches + V^T + q pre-scale
  postproc<<<dim3(S_LEN/4, 20), 256, 0, stream>>>(
      C1, cosb, sinb, qnw, knw, qb, kb, vtb, kcache, vcache);

  // flash attention + sigmoid gate -> attnb (S x H*HD bf16)
  attn_kernel<<<512, 256, 0, stream>>>(qb, kb, vtb, C1, attnb);

  // hidden_out = attnb @ Wo^T  (2048 x 2048, K=4096), 128x128 tile: 256 blocks
  gemm_bt<128,128,4,4><<<dim3(HID/128, S_LEN/128), 256, 0, stream>>>(
      attnb, wob, out, S_LEN, HID, NH*HD);
}

// Round 4
// 477.782 us; speedup vs baseline: 1.2268x; 1.0392x over previous
//
#include <hip/hip_runtime.h>

#define S_LEN 2048
#define HID 2048
#define NH 16
#define NKV 2
#define HD 256
#define MAXSEQ 4096
#define NALL 9216   // 8192 qg | 512 k | 512 v
#define RD 64

typedef __attribute__((ext_vector_type(8))) short short8_t;   // 8 bf16 (4 VGPRs)
typedef __attribute__((ext_vector_type(4))) float float4_t;   // MFMA C/D

// DPP cross-lane over a 16-lane row (VALU pipe, not LDS): xor1, xor2, half-mirror, mirror
#define DPPF(x, ctrl) __builtin_bit_cast(float, __builtin_amdgcn_update_dpp( \
    __builtin_bit_cast(int, x), __builtin_bit_cast(int, x), ctrl, 0xF, 0xF, false))

__device__ __forceinline__ unsigned short f2b(float f) {
  union { float f; unsigned u; } v; v.f = f;
  unsigned u = v.u;
  return (unsigned short)((u + 0x7FFFu + ((u >> 16) & 1u)) >> 16);  // RNE, finite data
}

__device__ __forceinline__ void gload_lds16(const void* g, void* l) {
  __builtin_amdgcn_global_load_lds(
      (const __attribute__((address_space(1))) void*)g,
      (__attribute__((address_space(3))) void*)l, 16, 0, 0);
}

// ---------------- fp32 -> bf16 convert ----------------
__global__ void cvt_bf16(const float* __restrict__ src, unsigned short* __restrict__ dst, int n4) {
  int i = blockIdx.x * blockDim.x + threadIdx.x;
  if (i < n4) {
    float4 v = ((const float4*)src)[i];
    short4 o;
    o.x = (short)f2b(v.x); o.y = (short)f2b(v.y);
    o.z = (short)f2b(v.z); o.w = (short)f2b(v.w);
    ((short4*)dst)[i] = o;
  }
}

// ---------------- bf16 GEMM, C = A * B^T  (A: MxK, B: NxK row-major, C: MxN f32) ----------------
// m97 structure + BK=64 + XOR-swizzled LDS (chunk' = chunk ^ (row&7)):
// 128B row stride => bank group = chunk'*4 (row-independent); 16 l15-lanes spread over
// all 8 chunk positions twice => 2-way = free (m136). Swizzle applied on the GLOBAL
// source column during global_load_lds staging (LDS side must stay lane-contiguous).
template<int BM, int BN, int MI, int NI>
__global__ __launch_bounds__(256, 2) void gemm_bt(
    const unsigned short* __restrict__ A, const unsigned short* __restrict__ B,
    float* __restrict__ C, int M, int N, int K) {
  constexpr int BK = 64;
  __shared__ unsigned short As[BM * BK];
  __shared__ unsigned short Bs[BN * BK];
  const int tid = threadIdx.x;
  const int lane = tid & 63;
  const int w = tid >> 6;
  const int wr = w >> 1, wc = w & 1;
  const int l15 = lane & 15, l4 = lane >> 4;
  const int M0 = blockIdx.y * BM, N0 = blockIdx.x * BN;
  float4_t acc[MI][NI] = {};
  for (int kt = 0; kt < K; kt += BK) {
    __syncthreads();
#pragma unroll
    for (int i = 0; i < BM/32; ++i) {            // A tile: BM rows x 64, 8 chunks/row
      int c = tid + i*256;
      int row = c >> 3;
      gload_lds16(A + (size_t)(M0 + row)*K + kt + ((c & 7) ^ (row & 7))*8, (char*)As + c*16);
    }
#pragma unroll
    for (int i = 0; i < BN/32; ++i) {
      int c = tid + i*256;
      int row = c >> 3;
      gload_lds16(B + (size_t)(N0 + row)*K + kt + ((c & 7) ^ (row & 7))*8, (char*)Bs + c*16);
    }
    __syncthreads();
#pragma unroll
    for (int ks = 0; ks < 2; ++ks) {             // two 32-k MFMA steps per BK=64 tile
      short8_t af[MI], bf[NI];
#pragma unroll
      for (int mi = 0; mi < MI; ++mi) {
        int row = wr*(BM/2) + mi*16 + l15;       // row&7 == l15&7
        af[mi] = *(const short8_t*)&As[row*BK + ((ks*4 + l4) ^ (l15 & 7))*8];
      }
#pragma unroll
      for (int ni = 0; ni < NI; ++ni) {
        int row = wc*(BN/2) + ni*16 + l15;
        bf[ni] = *(const short8_t*)&Bs[row*BK + ((ks*4 + l4) ^ (l15 & 7))*8];
      }
#pragma unroll
      for (int mi = 0; mi < MI; ++mi)
#pragma unroll
        for (int ni = 0; ni < NI; ++ni)
          acc[mi][ni] = __builtin_amdgcn_mfma_f32_16x16x32_bf16(af[mi], bf[ni], acc[mi][ni], 0, 0, 0);
    }
  }
  // C/D layout: col = lane&15, row = (lane>>4)*4 + r  [m89/m91 verified]
#pragma unroll
  for (int mi = 0; mi < MI; ++mi) {
    int rb = M0 + wr*(BM/2) + mi*16 + l4*4;
#pragma unroll
    for (int ni = 0; ni < NI; ++ni) {
      int col = N0 + wc*(BN/2) + ni*16 + l15;
#pragma unroll
      for (int r = 0; r < 4; ++r)
        C[(size_t)(rb + r)*N + col] = acc[mi][ni][r];
    }
  }
}

// ---------------- post: RMSNorm + RoPE + split + caches + V^T ----------------
// grid (S/4, 20): y = 0..15 q-head, 16..17 k, 18..19 v. one wave per (s,row).
__global__ void postproc(const float* __restrict__ C1,
                         const float* __restrict__ cosb, const float* __restrict__ sinb,
                         const float* __restrict__ qnw, const float* __restrict__ knw,
                         unsigned short* __restrict__ qb, unsigned short* __restrict__ kb,
                         unsigned short* __restrict__ vtb,
                         float* __restrict__ kcache, float* __restrict__ vcache) {
  const int w = threadIdx.x >> 6, lane = threadIdx.x & 63;
  const int s = blockIdx.x*4 + w;
  const int t = blockIdx.y;
  const int d = lane*4;
  const float* rowp;
  if (t < 16)      rowp = C1 + (size_t)s*NALL + t*512;           // q part of head t
  else if (t < 18) rowp = C1 + (size_t)s*NALL + 8192 + (t-16)*256;
  else             rowp = C1 + (size_t)s*NALL + 8704 + (t-18)*256;
  float4 x = *(const float4*)(rowp + d);
  if (t >= 18) {            // V: f32 cache + bf16 transposed (HD x S) for PV b-frags
    int kvi = t - 18;
    *(float4*)(vcache + (size_t)kvi*MAXSEQ*HD + (size_t)s*HD + d) = x;
    unsigned short* vt = vtb + (size_t)kvi*HD*S_LEN;
    vt[(size_t)(d+0)*S_LEN + s] = f2b(x.x);
    vt[(size_t)(d+1)*S_LEN + s] = f2b(x.y);
    vt[(size_t)(d+2)*S_LEN + s] = f2b(x.z);
    vt[(size_t)(d+3)*S_LEN + s] = f2b(x.w);
    return;
  }
  float ss = x.x*x.x + x.y*x.y + x.z*x.z + x.w*x.w;
#pragma unroll
  for (int o = 32; o >= 1; o >>= 1) ss += __shfl_xor(ss, o, 64);
  float rn = rsqrtf(ss*(1.0f/256.0f) + 1e-6f);
  const float* nw = (t < 16) ? qnw : knw;
  float4 g = *(const float4*)(nw + d);
  float4 y;
  y.x = x.x*rn*(1.f+g.x); y.y = x.y*rn*(1.f+g.y);
  y.z = x.z*rn*(1.f+g.z); y.w = x.w*rn*(1.f+g.w);
  // RoPE on dims < 64 (lanes 0..15); partner at d^32 lives at lane^8, same component
  float px = __shfl_xor(y.x, 8, 64);
  float py = __shfl_xor(y.y, 8, 64);
  float pz = __shfl_xor(y.z, 8, 64);
  float pw = __shfl_xor(y.w, 8, 64);
  if (lane < 16) {
    float sgn = (lane & 8) ? 1.f : -1.f;        // d>=32: +x[d-32]; d<32: -x[d+32]
    float4 cs = *(const float4*)(cosb + (size_t)s*RD + d);
    float4 sn = *(const float4*)(sinb + (size_t)s*RD + d);
    y.x = y.x*cs.x + sgn*px*sn.x;
    y.y = y.y*cs.y + sgn*py*sn.y;
    y.z = y.z*cs.z + sgn*pz*sn.z;
    y.w = y.w*cs.w + sgn*pw*sn.w;
  }
  if (t < 16) {
    const float qs = 0.0625f * 1.44269504088896f;   // SCALE * log2(e): softmax in exp2 domain
    short4 o;
    o.x = (short)f2b(y.x*qs); o.y = (short)f2b(y.y*qs);
    o.z = (short)f2b(y.z*qs); o.w = (short)f2b(y.w*qs);
    *(short4*)(qb + (size_t)t*S_LEN*HD + (size_t)s*HD + d) = o;
  } else {
    int kvi = t - 16;
    *(float4*)(kcache + (size_t)kvi*MAXSEQ*HD + (size_t)s*HD + d) = y;
    short4 o;
    o.x = (short)f2b(y.x); o.y = (short)f2b(y.y);
    o.z = (short)f2b(y.z); o.w = (short)f2b(y.w);
    *(short4*)(kb + (size_t)kvi*S_LEN*HD + (size_t)s*HD + d) = o;
  }
}

// ---------------- flash attention + fused sigmoid gate ----------------
// 1-D grid 512 blocks, 256 thr. Wave w owns q rows [q0+16w, q0+16w+16).
// Balance map: qt(2i)+qt(2i+1)=31 (adjacent blocks pair heavy+light — placement-robust;
// under round-robin placement (b, b+256) pairs sum <= 38 vs 33 ideal).
// LDS (XOR-swizzled, chunk' = chunk ^ (row&7), 16B chunks):
//   Ks 64x256 bf16 (32KB) | VTs 256x64 bf16 (32KB) | P 4 waves x 16x64 bf16 (8KB, private)
__global__ __launch_bounds__(256, 2) void attn_kernel(
    const unsigned short* __restrict__ qb, const unsigned short* __restrict__ kb,
    const unsigned short* __restrict__ vtb, const float* __restrict__ C1,
    unsigned short* __restrict__ attnb) {
  __shared__ char smem[73728];
  unsigned short* Ks  = (unsigned short*)smem;
  unsigned short* VTs = (unsigned short*)(smem + 32768);
  const int tid = threadIdx.x, lane = tid & 63, w = tid >> 6;
  const int l15 = lane & 15, l4 = lane >> 4;
  const int b = blockIdx.x;
  const int i2 = b >> 1;
  const int h = i2 & 15;
  const int t16 = i2 >> 4;                    // 0..15
  const int qt = (b & 1) ? (31 - t16) : t16;  // adjacent blocks: qt sums to 31
  const int kv = h >> 3;                      // GROUPS = 8
  const int q0 = qt * 64;
  const unsigned short* Qb = qb + (size_t)h*S_LEN*HD;
  const unsigned short* Kb = kb + (size_t)kv*S_LEN*HD;
  const unsigned short* Vb = vtb + (size_t)kv*HD*S_LEN;
  unsigned short* Pw = (unsigned short*)(smem + 65536 + w*2048);   // private 16x64 bf16
  const int qrow = q0 + w*16 + l15;
  short8_t qf[8];                             // Q fragment, A-layout: [m=l15][k=l4*8+j] per 32-k step
#pragma unroll
  for (int kk = 0; kk < 8; ++kk)
    qf[kk] = *(const short8_t*)(Qb + (size_t)qrow*HD + kk*32 + l4*8);
  float4_t oacc[16] = {};
  float m_run[4] = {-1e30f, -1e30f, -1e30f, -1e30f};
  float l_run[4] = {0.f, 0.f, 0.f, 0.f};
  for (int kbI = 0; kbI <= qt; ++kbI) {
    const int k0 = kbI * 64;
    __syncthreads();                          // prev iter's LDS reads done
#pragma unroll
    for (int i = 0; i < 8; ++i) {             // K tile: 64 rows x 256, swizzled source col
      int c = tid + i*256;
      int row = c >> 5;
      gload_lds16(Kb + (size_t)(k0 + row)*HD + ((c & 31) ^ (row & 7))*8, (char*)Ks + c*16);
    }
#pragma unroll
    for (int i = 0; i < 8; ++i) {             // V^T tile: 256 rows x 64, swizzled source col
      int c = tid + i*256;
      int row = c >> 3;
      gload_lds16(Vb + (size_t)row*S_LEN + k0 + ((c & 7) ^ (row & 7))*8, (char*)VTs + c*16);
    }
    __syncthreads();                          // staging drained
    float4_t sacc[4] = {};
#pragma unroll
    for (int nt = 0; nt < 4; ++nt)
#pragma unroll
      for (int kk = 0; kk < 8; ++kk) {
        // row = nt*16+l15, global chunk kk*4+l4 -> swizzled ^ (l15&7): conflict-free
        short8_t bfr = *(const short8_t*)&Ks[(nt*16 + l15)*HD + (((kk*4 + l4) ^ (l15 & 7)))*8];
        sacc[nt] = __builtin_amdgcn_mfma_f32_16x16x32_bf16(qf[kk], bfr, sacc[nt], 0, 0, 0);
      }
    if (kbI == qt) {                          // causal mask only on diagonal tile
#pragma unroll
      for (int nt = 0; nt < 4; ++nt)
#pragma unroll
        for (int r = 0; r < 4; ++r)
          if (nt*16 + l15 > w*16 + l4*4 + r) sacc[nt][r] = -1e30f;
    }
    float alpha[4], p[4][4];
#pragma unroll
    for (int r = 0; r < 4; ++r) {
      float m0 = fmaxf(fmaxf(sacc[0][r], sacc[1][r]), fmaxf(sacc[2][r], sacc[3][r]));
      m0 = fmaxf(m0, DPPF(m0, 0xB1));         // quad_perm xor1
      m0 = fmaxf(m0, DPPF(m0, 0x4E));         // quad_perm xor2
      m0 = fmaxf(m0, DPPF(m0, 0x141));        // row_half_mirror
      m0 = fmaxf(m0, DPPF(m0, 0x140));        // row_mirror -> full 16-lane max
      float mnew = fmaxf(m_run[r], m0);
      alpha[r] = exp2f(m_run[r] - mnew);
      m_run[r] = mnew;
      float sum = 0.f;
#pragma unroll
      for (int nt = 0; nt < 4; ++nt) {
        p[nt][r] = exp2f(sacc[nt][r] - mnew);
        sum += p[nt][r];
      }
      sum += DPPF(sum, 0xB1);
      sum += DPPF(sum, 0x4E);
      sum += DPPF(sum, 0x141);
      sum += DPPF(sum, 0x140);                // full 16-lane sum
      l_run[r] = l_run[r]*alpha[r] + sum;
    }
#pragma unroll
    for (int nt2 = 0; nt2 < 16; ++nt2) {
      oacc[nt2][0] *= alpha[0];
      oacc[nt2][1] *= alpha[1];
      oacc[nt2][2] *= alpha[2];
      oacc[nt2][3] *= alpha[3];
    }
    // P: D-layout -> A-layout via private LDS (no barrier: same-wave RAW, lgkmcnt suffices)
#pragma unroll
    for (int nt = 0; nt < 4; ++nt)
#pragma unroll
      for (int r = 0; r < 4; ++r) {
        int prow = l4*4 + r;
        int pcol = nt*16 + l15;
        Pw[prow*64 + (((pcol >> 3) ^ (prow & 7)))*8 + (pcol & 7)] = f2b(p[nt][r]);
      }
    short8_t pf0 = *(const short8_t*)&Pw[l15*64 + ((l4 ^ (l15 & 7)))*8];
    short8_t pf1 = *(const short8_t*)&Pw[l15*64 + (((l4 ^ 4) ^ (l15 & 7)))*8];
#pragma unroll
    for (int nt2 = 0; nt2 < 16; ++nt2) {
      int vrow = nt2*16 + l15;
      short8_t v0 = *(const short8_t*)&VTs[vrow*64 + ((l4 ^ (l15 & 7)))*8];
      short8_t v1 = *(const short8_t*)&VTs[vrow*64 + (((l4 ^ 4) ^ (l15 & 7)))*8];
      oacc[nt2] = __builtin_amdgcn_mfma_f32_16x16x32_bf16(pf0, v0, oacc[nt2], 0, 0, 0);
      oacc[nt2] = __builtin_amdgcn_mfma_f32_16x16x32_bf16(pf1, v1, oacc[nt2], 0, 0, 0);
    }
  }
  float inv_l[4];
#pragma unroll
  for (int r = 0; r < 4; ++r) inv_l[r] = 1.f / l_run[r];
  const int srow0 = q0 + w*16 + l4*4;
#pragma unroll
  for (int nt2 = 0; nt2 < 16; ++nt2) {
    int dim = nt2*16 + l15;
#pragma unroll
    for (int r = 0; r < 4; ++r) {
      int srow = srow0 + r;
      float gv = C1[(size_t)srow*NALL + h*512 + 256 + dim];  // gate pre-activation
      float sg = 1.f / (1.f + __expf(-gv));
      attnb[(size_t)srow*(NH*HD) + h*HD + dim] = f2b(oacc[nt2][r] * inv_l[r] * sg);
    }
  }
}

extern "C" void kernel_launch(void* const* d_in, const int* in_sizes, int n_in,
                              void* d_out, int out_size, void* d_ws, size_t ws_size,
                              hipStream_t stream) {
  const float* hidden = (const float*)d_in[0];
  const float* cosb   = (const float*)d_in[1];
  const float* sinb   = (const float*)d_in[2];
  const float* qw     = (const float*)d_in[3];
  const float* kw     = (const float*)d_in[4];
  const float* vw     = (const float*)d_in[5];
  const float* ow     = (const float*)d_in[6];
  const float* qnw    = (const float*)d_in[7];
  const float* knw    = (const float*)d_in[8];
  float* out    = (float*)d_out;
  float* kcache = out + (size_t)S_LEN*HID;
  float* vcache = kcache + (size_t)NKV*MAXSEQ*HD;

  char* ws = (char*)d_ws;
  size_t off = 0;
  auto alloc = [&](size_t bytes) -> char* {
    char* p = ws + off; off += (bytes + 255) & ~(size_t)255; return p;
  };
  unsigned short* hidb  = (unsigned short*)alloc((size_t)S_LEN*HID*2);     //  8 MB
  unsigned short* wallb = (unsigned short*)alloc((size_t)NALL*HID*2);      // 36 MB (q|k|v weights)
  unsigned short* wob   = (unsigned short*)alloc((size_t)HID*NH*HD*2);     // 16 MB
  float*          C1    = (float*)alloc((size_t)S_LEN*NALL*4);             // 72 MB
  unsigned short* qb    = (unsigned short*)alloc((size_t)NH*S_LEN*HD*2);   // 16 MB
  unsigned short* kb    = (unsigned short*)alloc((size_t)NKV*S_LEN*HD*2);  //  2 MB
  unsigned short* vtb   = (unsigned short*)alloc((size_t)NKV*HD*S_LEN*2);  //  2 MB
  unsigned short* attnb = (unsigned short*)alloc((size_t)S_LEN*NH*HD*2);   // 16 MB

  // fp32 -> bf16 conversions (weights concatenated: rows 0..8191 q, 8192..8703 k, 8704..9215 v)
  cvt_bf16<<<(S_LEN*HID/4 + 255)/256, 256, 0, stream>>>(hidden, hidb, S_LEN*HID/4);
  cvt_bf16<<<(8192*HID/4 + 255)/256, 256, 0, stream>>>(qw, wallb, 8192*HID/4);
  cvt_bf16<<<(512*HID/4 + 255)/256, 256, 0, stream>>>(kw, wallb + (size_t)8192*HID, 512*HID/4);
  cvt_bf16<<<(512*HID/4 + 255)/256, 256, 0, stream>>>(vw, wallb + (size_t)8704*HID, 512*HID/4);
  cvt_bf16<<<(HID*NH*HD/4 + 255)/256, 256, 0, stream>>>(ow, wob, HID*NH*HD/4);

  // zero the cache pad rows [S, MAX_SEQ)
  for (int kvi = 0; kvi < NKV; ++kvi) {
    hipMemsetAsync(kcache + (size_t)kvi*MAXSEQ*HD + (size_t)S_LEN*HD, 0,
                   (size_t)(MAXSEQ - S_LEN)*HD*4, stream);
    hipMemsetAsync(vcache + (size_t)kvi*MAXSEQ*HD + (size_t)S_LEN*HD, 0,
                   (size_t)(MAXSEQ - S_LEN)*HD*4, stream);
  }

  // fused QKV projection: C1 = hidden @ [Wq|Wk|Wv]^T  (2048 x 9216)
  gemm_bt<128,128,4,4><<<dim3(NALL/128, S_LEN/128), 256, 0, stream>>>(
      hidb, wallb, C1, S_LEN, NALL, HID);

  // RMSNorm + RoPE + caches + V^T + q pre-scale
  postproc<<<dim3(S_LEN/4, 20), 256, 0, stream>>>(
      C1, cosb, sinb, qnw, knw, qb, kb, vtb, kcache, vcache);

  // flash attention + sigmoid gate -> attnb (S x H*HD bf16)
  attn_kernel<<<512, 256, 0, stream>>>(qb, kb, vtb, C1, attnb);

  // hidden_out = attnb @ Wo^T  (2048 x 2048, K=4096), 128x128 tile: 256 blocks
  gemm_bt<128,128,4,4><<<dim3(HID/128, S_LEN/128), 256, 0, stream>>>(
      attnb, wob, out, S_LEN, HID, NH*HD);
}